// Round 7
// baseline (217.087 us; speedup 1.0000x reference)
//
#include <hip/hip_runtime.h>
#include <stdint.h>

#define NT 2048
#define DT 128

typedef __bf16 bf16x8 __attribute__((ext_vector_type(8)));
typedef __bf16 bf16x4 __attribute__((ext_vector_type(4)));
typedef __bf16 bf16x2 __attribute__((ext_vector_type(2)));
typedef float  f32x4  __attribute__((ext_vector_type(4)));
typedef float  f32x16 __attribute__((ext_vector_type(16)));

__device__ __forceinline__ float sigm(float x) {
    // sigmoid(x/sqrt(128)) = 1/(1 + exp2(x * -log2(e)/sqrt(128)))
    return __builtin_amdgcn_rcpf(1.0f + __builtin_amdgcn_exp2f(x * -0.12753139620763842f));
}
__device__ __forceinline__ int pk2f(float a, float b) {
    bf16x2 p; p[0] = (__bf16)a; p[1] = (__bf16)b;
    return __builtin_bit_cast(int, p);
}

// ===================== prep: layout conversion into ws =====================
// Qt[b][n][d] = bf16(Q[b][d][n])   (d contiguous)  — GEMM1 A-frags
// Kt[b][m][d] = bf16(K[b][d][m])   (d contiguous)  — GEMM1 B-frags (register)
// Vc[b][v][n] = bf16(V[b][v][n])   (n contiguous)  — GEMM2 A-frags
__global__ __launch_bounds__(256)
void prep(const float* __restrict__ Q, const float* __restrict__ K,
          const float* __restrict__ V, __bf16* __restrict__ Qt,
          __bf16* __restrict__ Kt, __bf16* __restrict__ Vc)
{
    const int bid = blockIdx.x;
    const int t   = threadIdx.x;
    if (bid < 1024) {
        __shared__ float T[64][65];
        const int mat  = bid & 1;
        const int bb   = (bid >> 1) & 7;
        const int tile = bid >> 4;            // 0..63
        const int d0   = (tile & 1) * 64;
        const int n0   = (tile >> 1) * 64;
        const float* src = (mat ? K : Q) + (size_t)bb * DT * NT;
        __bf16*      dst = (mat ? Kt : Qt) + (size_t)bb * NT * DT;
        #pragma unroll
        for (int i = 0; i < 16; ++i) {
            const int r = 4 * i + (t >> 6);
            T[r][t & 63] = src[(size_t)(d0 + r) * NT + n0 + (t & 63)];
        }
        __syncthreads();
        const int n  = t >> 2;
        const int dq = (t & 3) * 16;
        bf16x8 o0, o1;
        #pragma unroll
        for (int j = 0; j < 8; ++j) {
            o0[j] = (__bf16)T[dq + j][n];
            o1[j] = (__bf16)T[dq + 8 + j][n];
        }
        __bf16* orow = dst + (size_t)(n0 + n) * DT + d0 + dq;
        *(bf16x8*)orow       = o0;
        *(bf16x8*)(orow + 8) = o1;
    } else {
        const int gid = (bid - 1024) * 256 + t;
        const size_t total = (size_t)8 * DT * NT;
        for (size_t base = (size_t)gid * 4; base < total; base += (size_t)128 * 256 * 4) {
            const float4 f = *(const float4*)(V + base);
            bf16x4 o;
            o[0] = (__bf16)f.x; o[1] = (__bf16)f.y; o[2] = (__bf16)f.z; o[3] = (__bf16)f.w;
            *(bf16x4*)(Vc + base) = o;
        }
    }
}

// ===================== main: no LDS, no barriers =====================
// mfma_f32_16x16x32_bf16:
//  A: lane holds A[row=lane&15][k=(lane>>4)*8+j], j=0..7
//  B: lane holds B[k=(lane>>4)*8+j][col=lane&15]
//  C/D: col=lane&15, row=(lane>>4)*4+reg           [guide §3 / m89-verified]
// Block = 4 waves sharing (b, n-stream); wave w owns m-col m_w = 64*mt+16*w,
// v = 0..127 (8 oacc tiles). Qt/Vc fragment addresses are wave-independent ->
// the 4 waves' loads alias in L1.
__global__ __launch_bounds__(256, 4)
void attn_main(const __bf16* __restrict__ Qt, const __bf16* __restrict__ Kt,
               const __bf16* __restrict__ Vc, float* __restrict__ out)
{
    const int t = threadIdx.x;
    const int w = t >> 6;
    const int l = t & 63;
    const int g = l >> 4;       // quad 0..3
    const int c = l & 15;       // col

    const int bid = blockIdx.x;
    const int b   = bid & 7;              // XCD-pinned batch
    const int mt  = (bid >> 3) & 31;
    const int ns  = bid >> 8;             // 0..3
    const int m_w    = mt * 64 + w * 16;
    const int n_base = ns * 512;

    const __bf16* Qtb = Qt + (size_t)b * NT * DT;
    const __bf16* Ktb = Kt + (size_t)b * NT * DT;
    const __bf16* Vcb = Vc + (size_t)b * DT * NT;
    float*        Ob  = out + (size_t)b * DT * NT;

    // K B-frags, register resident: kf[ks] = K[d=32ks+8g+j][m_w+c]
    bf16x8 kf[4];
    #pragma unroll
    for (int ks = 0; ks < 4; ++ks)
        kf[ks] = *(const bf16x8*)&Ktb[(size_t)(m_w + c) * DT + ks * 32 + 8 * g];

    f32x4 oacc[8];
    #pragma unroll
    for (int vs = 0; vs < 8; ++vs)
        #pragma unroll
        for (int r = 0; r < 4; ++r) oacc[vs][r] = 0.0f;

    const int srcA = ((g & 1) << 5) + c;   // lane 16*(2*(g&1)) + c
    const int srcB = srcA + 16;
    const int sh   = g >> 1;

    #pragma unroll 2
    for (int it = 0; it < 16; ++it) {
        const int n0 = n_base + it * 32;

        // ---- GEMM1: S[n0+16*nsb+row][m_w+c], two 16-n subtiles
        f32x4 sacc[2];
        #pragma unroll
        for (int nsb = 0; nsb < 2; ++nsb) {
            #pragma unroll
            for (int r = 0; r < 4; ++r) sacc[nsb][r] = 0.0f;
            const __bf16* arow = &Qtb[(size_t)(n0 + 16 * nsb + c) * DT + 8 * g];
            #pragma unroll
            for (int ks = 0; ks < 4; ++ks) {
                const bf16x8 af = *(const bf16x8*)(arow + 32 * ks);
                sacc[nsb] = __builtin_amdgcn_mfma_f32_16x16x32_bf16(af, kf[ks], sacc[nsb], 0, 0, 0);
            }
        }

        // ---- sigmoid -> packed pairs P[nsb][p]: rows {4g+2p, 4g+2p+1}
        int P[2][2];
        #pragma unroll
        for (int nsb = 0; nsb < 2; ++nsb) {
            P[nsb][0] = pk2f(sigm(sacc[nsb][0]), sigm(sacc[nsb][1]));
            P[nsb][1] = pk2f(sigm(sacc[nsb][2]), sigm(sacc[nsb][3]));
        }

        // ---- C-layout -> GEMM2 B-layout, in-register (8 shfl + 4 selects)
        // dest lane (g,c) needs S[n=8g+j][m=c]: nsb = g>>1, src quad 2*(g&1)+(q>>1)
        union { int i[4]; bf16x8 v; } bs;
        {
            const int a0 = __shfl(P[0][0], srcA, 64), a1 = __shfl(P[1][0], srcA, 64);
            const int b0 = __shfl(P[0][1], srcA, 64), b1 = __shfl(P[1][1], srcA, 64);
            const int c0 = __shfl(P[0][0], srcB, 64), c1 = __shfl(P[1][0], srcB, 64);
            const int d0 = __shfl(P[0][1], srcB, 64), d1 = __shfl(P[1][1], srcB, 64);
            bs.i[0] = sh ? a1 : a0;
            bs.i[1] = sh ? b1 : b0;
            bs.i[2] = sh ? c1 : c0;
            bs.i[3] = sh ? d1 : d0;
        }

        // ---- GEMM2: oacc[vs] += V[16vs+row][n0+k] * S[k][m]
        #pragma unroll
        for (int vs = 0; vs < 8; ++vs) {
            const bf16x8 av = *(const bf16x8*)&Vcb[(size_t)(16 * vs + c) * NT + n0 + 8 * g];
            oacc[vs] = __builtin_amdgcn_mfma_f32_16x16x32_bf16(av, bs.v, oacc[vs], 0, 0, 0);
        }
    }

    // ---- epilogue: merge the 4 n-splits
    #pragma unroll
    for (int vs = 0; vs < 8; ++vs)
        #pragma unroll
        for (int r = 0; r < 4; ++r)
            atomicAdd(&Ob[(size_t)(16 * vs + 4 * g + r) * NT + m_w + c], oacc[vs][r]);
}

// ===================== fallback (R4 fused, proven) =====================
__global__ __launch_bounds__(512, 4)
void sig_attn_fused(const float* __restrict__ Q, const float* __restrict__ K,
                    const float* __restrict__ V, float* __restrict__ out)
{
    __shared__ __align__(16) __bf16 Qs[2][64 * 128];
    __shared__ __align__(16) __bf16 Vs[2][128 * 64];

    const int t = threadIdx.x;
    const int w = t >> 6, l = t & 63, lq = l >> 5, l31 = l & 31, lx = l ^ 32;
    const int wm = w & 3, wv = w >> 2;

    const int bid = blockIdx.x;
    const int b = bid & 7, mt = (bid >> 3) & 15, ns = bid >> 7;
    const int m_blk = mt * 128, n_base = ns * 512;

    const float* Qb = Q + (size_t)b * DT * NT;
    const float* Kb = K + (size_t)b * DT * NT;
    const float* Vb = V + (size_t)b * DT * NT;
    float*       Ob = out + (size_t)b * DT * NT;

    const int mrow = 32 * wm + l31;

    float  qp[16];
    float4 vp[4];
    {
        #pragma unroll
        for (int r = 0; r < 2; ++r)
            #pragma unroll
            for (int j = 0; j < 8; ++j)
                qp[r * 8 + j] = Qb[(size_t)(64 * r + 8 * w + j) * NT + n_base + l];
        const float* vb = Vb + (size_t)(t >> 2) * NT + n_base + 8 * (t & 3);
        vp[0] = *(const float4*)(vb);
        vp[1] = *(const float4*)(vb + 4);
        vp[2] = *(const float4*)(vb + 32);
        vp[3] = *(const float4*)(vb + 36);
    }

    bf16x8 kf[8];
    #pragma unroll
    for (int half = 0; half < 2; ++half) {
        float tmp[4][8];
        #pragma unroll
        for (int k2 = 0; k2 < 4; ++k2)
            #pragma unroll
            for (int j = 0; j < 8; ++j)
                tmp[k2][j] = Kb[(size_t)((half * 4 + k2) * 16 + lq * 8 + j) * NT + m_blk + mrow];
        #pragma unroll
        for (int k2 = 0; k2 < 4; ++k2) {
            bf16x8 f;
            #pragma unroll
            for (int j = 0; j < 8; ++j) f[j] = (__bf16)tmp[k2][j];
            kf[half * 4 + k2] = f;
        }
    }

    f32x16 oacc[2];
    #pragma unroll
    for (int tv = 0; tv < 2; ++tv)
        #pragma unroll
        for (int r = 0; r < 16; ++r) oacc[tv][r] = 0.0f;

    for (int it = 0; it < 8; ++it) {
        __bf16* Qbuf = Qs[it & 1];
        __bf16* Vbuf = Vs[it & 1];
        #pragma unroll
        for (int r = 0; r < 2; ++r) {
            bf16x8 pk;
            #pragma unroll
            for (int j = 0; j < 8; ++j) pk[j] = (__bf16)qp[r * 8 + j];
            *(bf16x8*)&Qbuf[l * 128 + (((8 * r + w) ^ (l & 15)) * 8)] = pk;
        }
        {
            const int v = t >> 2;
            #pragma unroll
            for (int u = 0; u < 2; ++u) {
                const int gg = (t & 3) + 4 * u;
                const float* s = (const float*)&vp[2 * u];
                bf16x8 pk;
                #pragma unroll
                for (int j = 0; j < 8; ++j) pk[j] = (__bf16)s[j];
                *(bf16x8*)&Vbuf[v * 64 + ((gg ^ (v & 7)) * 8)] = pk;
            }
        }
        __syncthreads();
        {
            const int n0 = n_base + ((it + 1) & 7) * 64;
            #pragma unroll
            for (int r = 0; r < 2; ++r)
                #pragma unroll
                for (int j = 0; j < 8; ++j)
                    qp[r * 8 + j] = Qb[(size_t)(64 * r + 8 * w + j) * NT + n0 + l];
            const float* vb = Vb + (size_t)(t >> 2) * NT + n0 + 8 * (t & 3);
            vp[0] = *(const float4*)(vb);
            vp[1] = *(const float4*)(vb + 4);
            vp[2] = *(const float4*)(vb + 32);
            vp[3] = *(const float4*)(vb + 36);
        }
        #pragma unroll
        for (int h = 0; h < 2; ++h) {
            f32x16 sacc;
            #pragma unroll
            for (int r = 0; r < 16; ++r) sacc[r] = 0.0f;
            const int nrow = 32 * h + l31;
            #pragma unroll
            for (int k = 0; k < 8; ++k) {
                const bf16x8 af =
                    *(const bf16x8*)&Qbuf[nrow * 128 + (((2 * k + lq) ^ (nrow & 15)) * 8)];
                sacc = __builtin_amdgcn_mfma_f32_32x32x16_bf16(af, kf[k], sacc, 0, 0, 0);
            }
            int Pi[8];
            #pragma unroll
            for (int i = 0; i < 8; ++i)
                Pi[i] = pk2f(sigm(sacc[2 * i]), sigm(sacc[2 * i + 1]));
            #pragma unroll
            for (int s = 0; s < 2; ++s) {
                const int x  = lq ? Pi[4 * s + 0] : Pi[4 * s + 2];
                const int y  = lq ? Pi[4 * s + 1] : Pi[4 * s + 3];
                const int xs = __shfl(x, lx, 64);
                const int ys = __shfl(y, lx, 64);
                union { int i[4]; bf16x8 v; } bf;
                bf.i[0] = lq ? xs : Pi[4 * s + 0];
                bf.i[1] = lq ? ys : Pi[4 * s + 1];
                bf.i[2] = lq ? Pi[4 * s + 2] : xs;
                bf.i[3] = lq ? Pi[4 * s + 3] : ys;
                const int sl  = ((4 * h + 2 * s + lq) ^ (l31 & 7)) * 8;
                const bf16x8 av0 = *(const bf16x8*)&Vbuf[(64 * wv + l31) * 64 + sl];
                const bf16x8 av1 = *(const bf16x8*)&Vbuf[(64 * wv + 32 + l31) * 64 + sl];
                oacc[0] = __builtin_amdgcn_mfma_f32_32x32x16_bf16(av0, bf.v, oacc[0], 0, 0, 0);
                oacc[1] = __builtin_amdgcn_mfma_f32_32x32x16_bf16(av1, bf.v, oacc[1], 0, 0, 0);
            }
        }
    }
    #pragma unroll
    for (int tv = 0; tv < 2; ++tv) {
        #pragma unroll
        for (int r = 0; r < 16; ++r) {
            const int v = 64 * wv + 32 * tv + (r & 3) + 8 * (r >> 2) + 4 * lq;
            atomicAdd(&Ob[(size_t)v * NT + m_blk + mrow], oacc[tv][r]);
        }
    }
}

extern "C" void kernel_launch(void* const* d_in, const int* in_sizes, int n_in,
                              void* d_out, int out_size, void* d_ws, size_t ws_size,
                              hipStream_t stream) {
    (void)in_sizes; (void)n_in;
    const float* Q = (const float*)d_in[0];
    const float* K = (const float*)d_in[1];
    const float* V = (const float*)d_in[2];
    float* O = (float*)d_out;

    const size_t arr = (size_t)8 * NT * DT * 2;    // 4 MB per bf16 array
    hipMemsetAsync(d_out, 0, (size_t)out_size * sizeof(float), stream);
    if (ws_size >= 3 * arr) {
        __bf16* Qt = (__bf16*)d_ws;
        __bf16* Kt = (__bf16*)((char*)d_ws + arr);
        __bf16* Vc = (__bf16*)((char*)d_ws + 2 * arr);
        prep<<<dim3(1152), dim3(256), 0, stream>>>(Q, K, V, Qt, Kt, Vc);
        attn_main<<<dim3(1024), dim3(256), 0, stream>>>(Qt, Kt, Vc, O);
    } else {
        sig_attn_fused<<<dim3(512), dim3(512), 0, stream>>>(Q, K, V, O);
    }
}

// Round 8
// 188.172 us; speedup vs baseline: 1.1537x; 1.1537x over previous
//
#include <hip/hip_runtime.h>
#include <stdint.h>

#define NT 2048
#define DT 128

typedef __bf16 bf16x8 __attribute__((ext_vector_type(8)));
typedef __bf16 bf16x2 __attribute__((ext_vector_type(2)));
typedef float  f32x16 __attribute__((ext_vector_type(16)));

__device__ __forceinline__ float sigm(float x) {
    // sigmoid(x/sqrt(128)) = 1/(1 + exp2(x * -log2(e)/sqrt(128)))
    return __builtin_amdgcn_rcpf(1.0f + __builtin_amdgcn_exp2f(x * -0.12753139620763842f));
}
__device__ __forceinline__ int pk2f(float a, float b) {
    bf16x2 p; p[0] = (__bf16)a; p[1] = (__bf16)b;
    return __builtin_bit_cast(int, p);
}

// mfma_f32_32x32x16_bf16:
//  A: lane holds A[row=lane&31][k=(lane>>5)*8+j]
//  B: lane holds B[k=(lane>>5)*8+j][col=lane&31]
//  C/D: col=lane&31, row=(reg&3)+8*(reg>>2)+4*(lane>>5)

// =================== prep: frag-major operand stores ===================
// Qf[b][nt64][ks8][lane64][8]  : A-frag elems Q[d=16ks+8(lane>>5)+j][n=32nt+(lane&31)]
// Kf[b][mc64][ks8][lane64][8]  : B-frag elems K[d=16ks+8(lane>>5)+j][m=32mc+(lane&31)]
// Vf[b][vt4][nk128][lane64][8] : A-frag elems V[v=32vt+(lane&31)][n=16nk+8(lane>>5)+j]
__global__ __launch_bounds__(256)
void prep(const float* __restrict__ Q, const float* __restrict__ K,
          const float* __restrict__ V, __bf16* __restrict__ Qf,
          __bf16* __restrict__ Kf, __bf16* __restrict__ Vf)
{
    const int bid = blockIdx.x;
    const int t   = threadIdx.x;
    if (bid < 1024) {                       // Q/K transpose via LDS tiles
        __shared__ float T[64][65];
        const int mat  = bid & 1;
        const int bb   = (bid >> 1) & 7;
        const int tile = bid >> 4;          // 0..63
        const int d0   = (tile & 1) * 64;
        const int n0   = (tile >> 1) * 64;
        const float* src = (mat ? K : Q) + (size_t)bb * DT * NT;
        __bf16*      dst = (mat ? Kf : Qf) + (size_t)bb * (64 * 8 * 512);
        #pragma unroll
        for (int i = 0; i < 16; ++i) {
            const int r = 4 * i + (t >> 6);
            T[r][t & 63] = src[(size_t)(d0 + r) * NT + n0 + (t & 63)];
        }
        __syncthreads();
        const int nloc = t >> 2;            // 0..63
        const int n    = n0 + nloc;         // global n (or m)
        const int dq   = (t & 3) * 16;
        #pragma unroll
        for (int h = 0; h < 2; ++h) {
            const int d = d0 + dq + 8 * h;  // 8-aligned d-run
            bf16x8 o;
            #pragma unroll
            for (int j = 0; j < 8; ++j) o[j] = (__bf16)T[dq + 8 * h + j][nloc];
            const int ks   = (d >> 4) & 7;
            const int lane = (n & 31) + 32 * ((d >> 3) & 1);
            *(bf16x8*)&dst[((size_t)((n >> 5) * 8 + ks)) * 512 + lane * 8] = o;
        }
    } else {                                // V: streaming cvt + reindex
        const int cid  = (bid - 1024) * 256 + t;   // 0..262143 (16B chunks)
        const int lane = cid & 63;
        const int nk   = (cid >> 6) & 127;
        const int vt   = (cid >> 13) & 3;
        const int b    = cid >> 15;
        const float* s = V + (size_t)b * DT * NT
                           + (size_t)(32 * vt + (lane & 31)) * NT
                           + 16 * nk + 8 * (lane >> 5);
        const float4 f0 = *(const float4*)s;
        const float4 f1 = *(const float4*)(s + 4);
        bf16x8 o;
        o[0] = (__bf16)f0.x; o[1] = (__bf16)f0.y; o[2] = (__bf16)f0.z; o[3] = (__bf16)f0.w;
        o[4] = (__bf16)f1.x; o[5] = (__bf16)f1.y; o[6] = (__bf16)f1.z; o[7] = (__bf16)f1.w;
        *(bf16x8*)&Vf[(size_t)cid * 8] = o;
    }
}

// =================== main: no LDS, no barriers, no dup ===================
// wave (wm, wnt): unique m-col mc = 2*mt+wm, nt stream = ns*16 + 2*i + wnt.
// Every fragment load = one contiguous 1KB dwordx4 (R7 lesson: no scatter).
__global__ __launch_bounds__(256, 3)
void attn_main(const __bf16* __restrict__ Qf, const __bf16* __restrict__ Kf,
               const __bf16* __restrict__ Vf, float* __restrict__ out)
{
    const int t   = threadIdx.x;
    const int w   = t >> 6;
    const int l   = t & 63;
    const int lq  = l >> 5;
    const int l31 = l & 31;
    const int lx  = l ^ 32;
    const int wm  = w & 1;
    const int wnt = w >> 1;

    const int bid = blockIdx.x;
    const int b   = bid & 7;              // XCD-pinned batch
    const int mt  = (bid >> 3) & 31;
    const int ns  = bid >> 8;             // 0..3
    const int mc  = 2 * mt + wm;          // m-col 0..63

    const __bf16* Qb = Qf + (size_t)b * (64 * 8 * 512);
    const __bf16* Vb = Vf + (size_t)b * (4 * 128 * 512);
    float*        Ob = out + (size_t)b * DT * NT;

    // K B-frags, register resident
    const __bf16* kfp = Kf + ((size_t)(b * 64 + mc) * 8) * 512 + l * 8;
    bf16x8 kf[8];
    #pragma unroll
    for (int ks = 0; ks < 8; ++ks)
        kf[ks] = *(const bf16x8*)(kfp + (size_t)ks * 512);

    f32x16 oacc[4];
    #pragma unroll
    for (int vt = 0; vt < 4; ++vt)
        #pragma unroll
        for (int r = 0; r < 16; ++r) oacc[vt][r] = 0.0f;

    #pragma unroll 2
    for (int i = 0; i < 8; ++i) {
        const int nt = ns * 16 + 2 * i + wnt;

        // GEMM1: sacc = S[32n-tile nt][m-col mc]
        const __bf16* ap = Qb + (size_t)nt * (8 * 512) + l * 8;
        f32x16 sacc;
        #pragma unroll
        for (int r = 0; r < 16; ++r) sacc[r] = 0.0f;
        #pragma unroll
        for (int ks = 0; ks < 8; ++ks) {
            const bf16x8 af = *(const bf16x8*)(ap + (size_t)ks * 512);
            sacc = __builtin_amdgcn_mfma_f32_32x32x16_bf16(af, kf[ks], sacc, 0, 0, 0);
        }

        // sigmoid -> packed row-pairs (C-layout rows {2i,2i+1} of col m)
        int Pi[8];
        #pragma unroll
        for (int ii = 0; ii < 8; ++ii)
            Pi[ii] = pk2f(sigm(sacc[2 * ii]), sigm(sacc[2 * ii + 1]));

        // per 16-k step: in-register C->B transform (R4-verified) + GEMM2
        #pragma unroll
        for (int s = 0; s < 2; ++s) {
            const int x  = lq ? Pi[4 * s + 0] : Pi[4 * s + 2];
            const int y  = lq ? Pi[4 * s + 1] : Pi[4 * s + 3];
            const int xs = __shfl(x, lx, 64);
            const int ys = __shfl(y, lx, 64);
            union { int i[4]; bf16x8 v; } bs;
            bs.i[0] = lq ? xs : Pi[4 * s + 0];
            bs.i[1] = lq ? ys : Pi[4 * s + 1];
            bs.i[2] = lq ? Pi[4 * s + 2] : xs;
            bs.i[3] = lq ? Pi[4 * s + 3] : ys;

            const __bf16* vp = Vb + (size_t)(2 * nt + s) * 512 + l * 8;
            #pragma unroll
            for (int vt = 0; vt < 4; ++vt) {
                const bf16x8 av = *(const bf16x8*)(vp + (size_t)vt * (128 * 512));
                oacc[vt] = __builtin_amdgcn_mfma_f32_32x32x16_bf16(av, bs.v, oacc[vt], 0, 0, 0);
            }
        }
    }

    // epilogue: merge 4 n-splits
    #pragma unroll
    for (int vt = 0; vt < 4; ++vt)
        #pragma unroll
        for (int r = 0; r < 16; ++r) {
            const int v = 32 * vt + (r & 3) + 8 * (r >> 2) + 4 * lq;
            atomicAdd(&Ob[(size_t)v * NT + mc * 32 + l31], oacc[vt][r]);
        }
}

// =================== fallback (R4 fused, proven 63 us) ===================
__global__ __launch_bounds__(512, 4)
void sig_attn_fused(const float* __restrict__ Q, const float* __restrict__ K,
                    const float* __restrict__ V, float* __restrict__ out)
{
    __shared__ __align__(16) __bf16 Qs[2][64 * 128];
    __shared__ __align__(16) __bf16 Vs[2][128 * 64];
    const int t = threadIdx.x;
    const int w = t >> 6, l = t & 63, lq = l >> 5, l31 = l & 31, lx = l ^ 32;
    const int wm = w & 3, wv = w >> 2;
    const int bid = blockIdx.x;
    const int b = bid & 7, mt = (bid >> 3) & 15, ns = bid >> 7;
    const int m_blk = mt * 128, n_base = ns * 512;
    const float* Qb = Q + (size_t)b * DT * NT;
    const float* Kb = K + (size_t)b * DT * NT;
    const float* Vb = V + (size_t)b * DT * NT;
    float*       Ob = out + (size_t)b * DT * NT;
    const int mrow = 32 * wm + l31;
    float  qp[16];
    float4 vp[4];
    {
        #pragma unroll
        for (int r = 0; r < 2; ++r)
            #pragma unroll
            for (int j = 0; j < 8; ++j)
                qp[r * 8 + j] = Qb[(size_t)(64 * r + 8 * w + j) * NT + n_base + l];
        const float* vb = Vb + (size_t)(t >> 2) * NT + n_base + 8 * (t & 3);
        vp[0] = *(const float4*)(vb);     vp[1] = *(const float4*)(vb + 4);
        vp[2] = *(const float4*)(vb + 32); vp[3] = *(const float4*)(vb + 36);
    }
    bf16x8 kf[8];
    #pragma unroll
    for (int half = 0; half < 2; ++half) {
        float tmp[4][8];
        #pragma unroll
        for (int k2 = 0; k2 < 4; ++k2)
            #pragma unroll
            for (int j = 0; j < 8; ++j)
                tmp[k2][j] = Kb[(size_t)((half * 4 + k2) * 16 + lq * 8 + j) * NT + m_blk + mrow];
        #pragma unroll
        for (int k2 = 0; k2 < 4; ++k2) {
            bf16x8 f;
            #pragma unroll
            for (int j = 0; j < 8; ++j) f[j] = (__bf16)tmp[k2][j];
            kf[half * 4 + k2] = f;
        }
    }
    f32x16 oacc[2];
    #pragma unroll
    for (int tv = 0; tv < 2; ++tv)
        #pragma unroll
        for (int r = 0; r < 16; ++r) oacc[tv][r] = 0.0f;
    for (int it = 0; it < 8; ++it) {
        __bf16* Qbuf = Qs[it & 1];
        __bf16* Vbuf = Vs[it & 1];
        #pragma unroll
        for (int r = 0; r < 2; ++r) {
            bf16x8 pk;
            #pragma unroll
            for (int j = 0; j < 8; ++j) pk[j] = (__bf16)qp[r * 8 + j];
            *(bf16x8*)&Qbuf[l * 128 + (((8 * r + w) ^ (l & 15)) * 8)] = pk;
        }
        {
            const int v = t >> 2;
            #pragma unroll
            for (int u = 0; u < 2; ++u) {
                const int g = (t & 3) + 4 * u;
                const float* s = (const float*)&vp[2 * u];
                bf16x8 pk;
                #pragma unroll
                for (int j = 0; j < 8; ++j) pk[j] = (__bf16)s[j];
                *(bf16x8*)&Vbuf[v * 64 + ((g ^ (v & 7)) * 8)] = pk;
            }
        }
        __syncthreads();
        {
            const int n0 = n_base + ((it + 1) & 7) * 64;
            #pragma unroll
            for (int r = 0; r < 2; ++r)
                #pragma unroll
                for (int j = 0; j < 8; ++j)
                    qp[r * 8 + j] = Qb[(size_t)(64 * r + 8 * w + j) * NT + n0 + l];
            const float* vb = Vb + (size_t)(t >> 2) * NT + n0 + 8 * (t & 3);
            vp[0] = *(const float4*)(vb);     vp[1] = *(const float4*)(vb + 4);
            vp[2] = *(const float4*)(vb + 32); vp[3] = *(const float4*)(vb + 36);
        }
        #pragma unroll
        for (int h = 0; h < 2; ++h) {
            f32x16 sacc;
            #pragma unroll
            for (int r = 0; r < 16; ++r) sacc[r] = 0.0f;
            const int nrow = 32 * h + l31;
            #pragma unroll
            for (int k = 0; k < 8; ++k) {
                const bf16x8 af =
                    *(const bf16x8*)&Qbuf[nrow * 128 + (((2 * k + lq) ^ (nrow & 15)) * 8)];
                sacc = __builtin_amdgcn_mfma_f32_32x32x16_bf16(af, kf[k], sacc, 0, 0, 0);
            }
            int Pi[8];
            #pragma unroll
            for (int i = 0; i < 8; ++i)
                Pi[i] = pk2f(sigm(sacc[2 * i]), sigm(sacc[2 * i + 1]));
            #pragma unroll
            for (int s = 0; s < 2; ++s) {
                const int x  = lq ? Pi[4 * s + 0] : Pi[4 * s + 2];
                const int y  = lq ? Pi[4 * s + 1] : Pi[4 * s + 3];
                const int xs = __shfl(x, lx, 64);
                const int ys = __shfl(y, lx, 64);
                union { int i[4]; bf16x8 v; } bf;
                bf.i[0] = lq ? xs : Pi[4 * s + 0];
                bf.i[1] = lq ? ys : Pi[4 * s + 1];
                bf.i[2] = lq ? Pi[4 * s + 2] : xs;
                bf.i[3] = lq ? Pi[4 * s + 3] : ys;
                const int sl  = ((4 * h + 2 * s + lq) ^ (l31 & 7)) * 8;
                const bf16x8 av0 = *(const bf16x8*)&Vbuf[(64 * wv + l31) * 64 + sl];
                const bf16x8 av1 = *(const bf16x8*)&Vbuf[(64 * wv + 32 + l31) * 64 + sl];
                oacc[0] = __builtin_amdgcn_mfma_f32_32x32x16_bf16(av0, bf.v, oacc[0], 0, 0, 0);
                oacc[1] = __builtin_amdgcn_mfma_f32_32x32x16_bf16(av1, bf.v, oacc[1], 0, 0, 0);
            }
        }
    }
    #pragma unroll
    for (int tv = 0; tv < 2; ++tv) {
        #pragma unroll
        for (int r = 0; r < 16; ++r) {
            const int v = 64 * wv + 32 * tv + (r & 3) + 8 * (r >> 2) + 4 * lq;
            atomicAdd(&Ob[(size_t)v * NT + m_blk + mrow], oacc[tv][r]);
        }
    }
}

extern "C" void kernel_launch(void* const* d_in, const int* in_sizes, int n_in,
                              void* d_out, int out_size, void* d_ws, size_t ws_size,
                              hipStream_t stream) {
    (void)in_sizes; (void)n_in;
    const float* Q = (const float*)d_in[0];
    const float* K = (const float*)d_in[1];
    const float* V = (const float*)d_in[2];
    float* O = (float*)d_out;

    const size_t arr = (size_t)8 * 64 * 8 * 512 * 2;   // 4 MB per frag array
    hipMemsetAsync(d_out, 0, (size_t)out_size * sizeof(float), stream);
    if (ws_size >= 3 * arr) {
        __bf16* Qfp = (__bf16*)d_ws;
        __bf16* Kfp = (__bf16*)((char*)d_ws + arr);
        __bf16* Vfp = (__bf16*)((char*)d_ws + 2 * arr);
        prep<<<dim3(2048), dim3(256), 0, stream>>>(Q, K, V, Qfp, Kfp, Vfp);
        attn_main<<<dim3(1024), dim3(256), 0, stream>>>(Qfp, Kfp, Vfp, O);
    } else {
        sig_attn_fused<<<dim3(512), dim3(512), 0, stream>>>(Q, K, V, O);
    }
}